// Round 7
// baseline (301.430 us; speedup 1.0000x reference)
//
#include <hip/hip_runtime.h>
#include <hip/hip_bf16.h>
#include <stdint.h>

typedef __attribute__((ext_vector_type(8))) short short8v;     // 8 x bf16 (MFMA A/B frag)
typedef __attribute__((ext_vector_type(4))) float float4v;     // MFMA C/D frag / vec loads
typedef __attribute__((ext_vector_type(4))) unsigned short ushort4v;
typedef __attribute__((ext_vector_type(4))) unsigned int uint4v;
typedef __attribute__((ext_vector_type(2))) unsigned int uint2v;

#define FINF __builtin_huge_valf()
#define BB 64
#define NN 512
#define DD 256
#define TT_SKEW 640   // skew rows: t = r + (j>>2) in [0, 511+127] -> 640

// ws layout (bytes):
//   [0,        16777216)  xnb bf16 [B][N][D]
//   [16777216, 33554432)  ynb bf16 [B][N][D]
//   [33554432, 75497472)  cost_skew bf16 [B][640][512]  (cell (r,j) at row t=r+(j>>2), col j)
//   [75497472, 75497728)  negbuf f32 [64]

static __device__ __forceinline__ unsigned short f2bf(float f) {
  union { float f; uint32_t u; } a; a.f = f;
  uint32_t r = a.u + 0x7fffu + ((a.u >> 16) & 1u);   // RNE
  return (unsigned short)(r >> 16);
}
static __device__ __forceinline__ float bf2f(uint16_t v) {
  return __uint_as_float(((uint32_t)v) << 16);
}

// ---------------- Kernel 0: zero the skew-layout pad cells ----------------
// Row t<128: cols [4(t+1), 512) are pad; row t in [512,640): cols [0, 4(t-511)).
__global__ __launch_bounds__(64) void pad_zero_kernel(uint16_t* __restrict__ skew)
{
  const int bid = blockIdx.x;
  const int b = bid >> 8, k = bid & 255;
  const int t   = (k < 128) ? k : (384 + k);          // 0..127 or 512..639
  const int jlo = (k < 128) ? 4 * (k + 1) : 0;
  const int jhi = (k < 128) ? 512 : 4 * (k - 127);
  uint16_t* p = skew + ((size_t)b * TT_SKEW + t) * NN;
  for (int j = jlo + (int)threadIdx.x * 4; j < jhi; j += 256)
    *(ushort4v*)(p + j) = (ushort4v){0, 0, 0, 0};
}

// ---------------- Kernel 1: row-normalize + cast to bf16 ----------------
__global__ __launch_bounds__(256) void norm_cast_kernel(
    const float* __restrict__ x, const float* __restrict__ y,
    uint16_t* __restrict__ xnb, uint16_t* __restrict__ ynb)
{
  const int wave = threadIdx.x >> 6, lane = threadIdx.x & 63;
  const int row = blockIdx.x * 4 + wave;
  const float* src; uint16_t* dst;
  if (row < BB * NN) { src = x + (size_t)row * DD;            dst = xnb + (size_t)row * DD; }
  else               { src = y + (size_t)(row - BB*NN) * DD;  dst = ynb + (size_t)(row - BB*NN) * DD; }
  const float4v v = *(const float4v*)(src + lane * 4);
  float s = v[0]*v[0] + v[1]*v[1] + v[2]*v[2] + v[3]*v[3];
  #pragma unroll
  for (int d = 1; d < 64; d <<= 1) s += __shfl_xor(s, d, 64);
  const float inv = 1.0f / fmaxf(sqrtf(s), 1e-8f);
  ushort4v o;
  o[0] = f2bf(v[0] * inv); o[1] = f2bf(v[1] * inv);
  o[2] = f2bf(v[2] * inv); o[3] = f2bf(v[3] * inv);
  *(ushort4v*)(dst + lane * 4) = o;
}

// ---------------- Kernel 2: cost = 1 - xn·yn -> bf16 skewed layout ----------------
__global__ __launch_bounds__(256) void gemm_cost_kernel(
    const uint16_t* __restrict__ xnb, const uint16_t* __restrict__ ynb,
    uint16_t* __restrict__ skew)
{
  __shared__ uint16_t As[128 * 32];
  __shared__ uint16_t Bs[128 * 32];
  const int bid = blockIdx.x;
  const int b = bid >> 4, tm = (bid >> 2) & 3, tn = bid & 3;
  const int tid = threadIdx.x, wave = tid >> 6, lane = tid & 63;
  const int wr = wave >> 1, wc = wave & 1;

  const char* Ab = (const char*)(xnb + (size_t)b * NN * DD + (size_t)tm * 128 * DD);
  const char* Bb = (const char*)(ynb + (size_t)b * NN * DD + (size_t)tn * 128 * DD);

  float4v acc[4][4];
  #pragma unroll
  for (int i = 0; i < 4; i++)
    #pragma unroll
    for (int j = 0; j < 4; j++) acc[i][j] = (float4v){0.f, 0.f, 0.f, 0.f};

  const int seg0 = wave * 2;
  const int o0 = seg0 * 1024 + lane * 16;
  const int o1 = o0 + 1024;
  const int r0 = o0 >> 6, c0 = o0 & 63;
  const int r1 = o1 >> 6, c1 = o1 & 63;

  for (int kk = 0; kk < 8; kk++) {
    const int kb = kk * 64;
    __builtin_amdgcn_global_load_lds(
        (const __attribute__((address_space(1))) uint32_t*)(Ab + (size_t)r0 * 512 + kb + c0),
        (__attribute__((address_space(3))) uint32_t*)((char*)As + seg0 * 1024), 16, 0, 0);
    __builtin_amdgcn_global_load_lds(
        (const __attribute__((address_space(1))) uint32_t*)(Ab + (size_t)r1 * 512 + kb + c1),
        (__attribute__((address_space(3))) uint32_t*)((char*)As + (seg0 + 1) * 1024), 16, 0, 0);
    __builtin_amdgcn_global_load_lds(
        (const __attribute__((address_space(1))) uint32_t*)(Bb + (size_t)r0 * 512 + kb + c0),
        (__attribute__((address_space(3))) uint32_t*)((char*)Bs + seg0 * 1024), 16, 0, 0);
    __builtin_amdgcn_global_load_lds(
        (const __attribute__((address_space(1))) uint32_t*)(Bb + (size_t)r1 * 512 + kb + c1),
        (__attribute__((address_space(3))) uint32_t*)((char*)Bs + (seg0 + 1) * 1024), 16, 0, 0);
    __syncthreads();

    short8v af[4], bfr[4];
    #pragma unroll
    for (int mi = 0; mi < 4; mi++) {
      const int rr = wr * 64 + mi * 16 + (lane & 15);
      af[mi] = *(const short8v*)((const char*)As + rr * 64 + (lane >> 4) * 16);
    }
    #pragma unroll
    for (int nj = 0; nj < 4; nj++) {
      const int rr = wc * 64 + nj * 16 + (lane & 15);
      bfr[nj] = *(const short8v*)((const char*)Bs + rr * 64 + (lane >> 4) * 16);
    }
    #pragma unroll
    for (int mi = 0; mi < 4; mi++)
      #pragma unroll
      for (int nj = 0; nj < 4; nj++)
        acc[mi][nj] = __builtin_amdgcn_mfma_f32_16x16x32_bf16(af[mi], bfr[nj], acc[mi][nj], 0, 0, 0);
    __syncthreads();
  }

  uint16_t* Cb = skew + (size_t)b * TT_SKEW * NN;
  #pragma unroll
  for (int mi = 0; mi < 4; mi++)
    #pragma unroll
    for (int nj = 0; nj < 4; nj++) {
      const int cc = tn * 128 + wc * 64 + nj * 16 + (lane & 15);
      const int lg = cc >> 2;
      #pragma unroll
      for (int v = 0; v < 4; v++) {
        const int rr = tm * 128 + wr * 64 + mi * 16 + (lane >> 4) * 4 + v;
        Cb[(size_t)(rr + lg) * NN + cc] = f2bf(1.0f - acc[mi][nj][v]);
      }
    }
}

// ---------------- Kernel 3: neg[b] = LSE over column sums ----------------
__global__ __launch_bounds__(256) void neg_lse_kernel(
    const uint16_t* __restrict__ skew, float* __restrict__ negbuf)
{
  __shared__ float sm[8];
  const int b = blockIdx.x, tid = threadIdx.x;
  const int wave = tid >> 6, lane = tid & 63;
  const uint32_t* p = (const uint32_t*)(skew + (size_t)b * TT_SKEW * NN) + tid;
  float s0 = 0.f, s1 = 0.f;
  #pragma unroll 8
  for (int t = 0; t < TT_SKEW; ++t) {
    const uint32_t w = p[t * 256];
    s0 += __uint_as_float(w << 16);
    s1 += __uint_as_float(w & 0xFFFF0000u);
  }
  float m = fmaxf(s0, s1);
  #pragma unroll
  for (int d = 1; d < 64; d <<= 1) m = fmaxf(m, __shfl_xor(m, d, 64));
  if (lane == 0) sm[wave] = m;
  __syncthreads();
  m = fmaxf(fmaxf(sm[0], sm[1]), fmaxf(sm[2], sm[3]));
  float e = expf(s0 - m) + expf(s1 - m);
  #pragma unroll
  for (int d = 1; d < 64; d <<= 1) e += __shfl_xor(e, d, 64);
  if (lane == 0) sm[4 + wave] = e;
  __syncthreads();
  if (tid == 0) negbuf[b] = m + logf(sm[4] + sm[5] + sm[6] + sm[7]);
}

// ---------------- Kernel 4: DTW forward (2 waves/batch) + backtrack + pos LSE ----
// Block = 128 thr = 2 waves. Wave w owns cols [256w, 256w+256), lane: 4 cols.
// Global step g: wave w consumes skew row t = g - 8w (4-col-group skew layout
// bakes the lane/group stagger). Boundary tc (col 255) passes wave0->wave1 via
// LDS hand[512]; __syncthreads() every 4 steps + Delta=8 guarantees ordering.
// 8-deep register ring, refill clamped to row 639 so exactly 8 loads are in
// flight at every consume -> vmcnt(7) is always exact.
// LDS: dec[512rows packed 2/row][128 grp]u8 = 64KB | rlo | rhi | colpos | hand | red
__global__ __launch_bounds__(128, 1) void dtw_kernel(
    const uint16_t* __restrict__ skew, const float* __restrict__ negbuf,
    float* __restrict__ out)
{
  extern __shared__ char lds_raw[];
  float* hand = (float*)(lds_raw + 69632);          // [512] f32
  const int tid = threadIdx.x;
  const int wv = tid >> 6, l = tid & 63;
  const int gidx = tid;                              // 4-col group index 0..127
  const int b = blockIdx.x;
  const uint16_t* csk = skew + (size_t)b * TT_SKEW * NN;
  const uint64_t base = (uint64_t)(uintptr_t)csk;
  const bool is0 = (l == 0);
  const bool w1 = (wv == 1);
  const int delta = wv << 3;                         // 0 or 8

  const uint32_t voff_base = 8u * (uint32_t)gidx;    // lane's 8B within a row
  uint2v ring[8];
  #pragma unroll
  for (int i = 0; i < 8; ++i) {
    const uint32_t vo = voff_base + (uint32_t)i * 1024u;
    asm volatile("global_load_dwordx2 %0, %1, %2"
                 : "=v"(ring[i]) : "v"(vo), "s"(base));
  }

  float tp0 = FINF, tp1 = FINF, tp2 = FINF, tp3 = FINF;
  float cur_last = FINF, sp_carry = FINF, p_carry = FINF, pref = FINF;
  const uint32_t dump_addr = 71680u + (((uint32_t)gidx) << 1);

  for (int g0 = 0; g0 < 648; g0 += 8) {
    #pragma unroll
    for (int u = 0; u < 8; ++u) {
      if (u == 0 || u == 4) __syncthreads();
      const int t = g0 + u - delta;
      if (t >= 0 && t < TT_SKEW) {                   // wave-uniform
        asm volatile("s_waitcnt vmcnt(7)" : "+v"(ring[u]));
        const uint2v cur = ring[u];

        const float c0 = __uint_as_float(cur[0] << 16);
        const float c1 = __uint_as_float(cur[0] & 0xFFFF0000u);
        const float c2 = __uint_as_float(cur[1] << 16);
        const float c3 = __uint_as_float(cur[1] & 0xFFFF0000u);
        const float S0 = c0, S1 = S0 + c1, S2 = S1 + c2, S3 = S2 + c3;

        const float sh_raw = __shfl_up(cur_last, 1, 64);
        const float ovr_c = w1 ? pref : ((t == 0) ? 0.0f : FINF);
        const float sh_c = is0 ? ovr_c : sh_raw;
        const float sh_p = is0 ? (w1 ? p_carry : FINF) : sp_carry;
        p_carry = ovr_c;
        sp_carry = sh_c;

        const uint32_t rlane = (uint32_t)(t - gidx);
        const bool valid = rlane < 512u;

        const float mu0 = fminf(sh_p, tp0), mu1 = fminf(tp0, tp1);
        const float mu2 = fminf(tp1, tp2), mu3 = fminf(tp2, tp3);
        const float w0c = mu0, w1c = mu1 - S0, w2c = mu2 - S1, w3c = mu3 - S2;
        const float PW1 = fminf(w0c, w1c), PW2 = fminf(PW1, w2c), PW3 = fminf(PW2, w3c);
        const float tn0 = fminf(w0c, sh_c) + S0;
        const float tn1 = fminf(PW1, sh_c) + S1;
        const float tn2 = fminf(PW2, sh_c) + S2;
        const float tn3 = fminf(PW3, sh_c) + S3;

        // decisions: dd = (lc < mu) ? 2 : (up < dcp ? 1 : 0)  (== ref chain)
        const uint32_t d0 = (sh_c < mu0) ? 2u : ((tp0 < sh_p) ? 1u : 0u);
        const uint32_t d1 = (tn0 < mu1) ? 2u : ((tp1 < tp0) ? 1u : 0u);
        const uint32_t d2 = (tn1 < mu2) ? 2u : ((tp2 < tp1) ? 1u : 0u);
        const uint32_t d3 = (tn2 < mu3) ? 2u : ((tp3 < tp2) ? 1u : 0u);
        const uint32_t byte = d0 | (d1 << 2) | (d2 << 4) | (d3 << 6);
        const uint32_t wbyte = ((rlane & ~1u) << 7) | (((uint32_t)gidx) << 1) | (rlane & 1u);
        *(uint8_t*)(lds_raw + (valid ? wbyte : dump_addr)) = (uint8_t)byte;

        tp0 = valid ? tn0 : tp0; tp1 = valid ? tn1 : tp1;
        tp2 = valid ? tn2 : tp2; tp3 = valid ? tn3 : tp3;
        cur_last = tp3;
        if (gidx == 63 && valid) hand[rlane] = cur_last;  // wave0 right edge

        // prefetch next step's handoff: r_next = (t+1) - 64 -> hand[t-63]
        {
          int hidx = t - 63; hidx = (hidx < 0) ? 0 : ((hidx > 511) ? 511 : hidx);
          pref = hand[hidx];
        }
        // refill: row t+8 (clamped) keeps exactly 8 loads in flight
        {
          const int rrow = (t + 8 < TT_SKEW) ? t + 8 : TT_SKEW - 1;
          const uint32_t vo = voff_base + ((uint32_t)rrow << 10);
          asm volatile("global_load_dwordx2 %0, %1, %2"
                       : "=v"(ring[u]) : "v"(vo), "s"(base));
        }
      }
    }
  }
  asm volatile("s_waitcnt vmcnt(0)" ::: "memory");
  __syncthreads();

  uint16_t* rlo    = (uint16_t*)(lds_raw + 65536);
  uint16_t* rhi    = (uint16_t*)(lds_raw + 66560);
  float*    colpos = (float*)  (lds_raw + 67584);
  float*    red    = (float*)  (lds_raw + 71680);
  const uint32_t* dec32 = (const uint32_t*)lds_raw;

  for (int r = tid; r < NN; r += 128) { rlo[r] = 1; rhi[r] = 0; colpos[r] = 0.0f; }
  __syncthreads();
  if (tid == 0) {
    int i = NN - 1, j = NN - 1, hicur = NN - 1;
    int cidx = -1; uint32_t cw = 0;
    while (i > 0 && j > 0) {
      const int widx = (i >> 1) * 64 + (j >> 3);
      if (widx != cidx) { cw = dec32[widx]; cidx = widx; }
      // byte_in_word = ((j>>2)&1)*2 + (i&1); bit = byte*8 + (j&3)*2
      const uint32_t dd = (cw >> ((((j >> 2) & 1) << 4) + ((i & 1) << 3) + ((j & 3) << 1))) & 3u;
      if (dd == 2u) { j--; }           // left: stay in row
      else {
        rlo[i] = (uint16_t)j; rhi[i] = (uint16_t)hicur;  // leave row i
        i--;
        if (dd == 0u) j--;             // diag also moves left
        hicur = j;                     // entry column of new row
      }
    }
    rlo[i] = (uint16_t)j; rhi[i] = (uint16_t)hicur;      // pending row at exit
  }
  __syncthreads();
  for (int r = tid; r < NN; r += 128) {
    const int lo = rlo[r], hi = rhi[r];
    for (int j = lo; j <= hi; j++) {
      const float cv = bf2f(csk[(size_t)(r + (j >> 2)) * NN + j]);
      atomicAdd(&colpos[j], cv);
    }
  }
  if (tid == 0 && rlo[0] != 0) atomicAdd(&colpos[0], bf2f(csk[0]));
  __syncthreads();

  // ---- pos = logsumexp over colpos (128 threads) ----
  float mx2 = -FINF;
  float mv[4];
  #pragma unroll
  for (int k = 0; k < 4; k++) { mv[k] = colpos[tid + 128 * k]; mx2 = fmaxf(mx2, mv[k]); }
  #pragma unroll
  for (int d = 1; d < 64; d <<= 1) mx2 = fmaxf(mx2, __shfl_xor(mx2, d, 64));
  if (l == 0) red[wv] = mx2;
  __syncthreads();
  mx2 = fmaxf(red[0], red[1]);
  float se2 = 0.f;
  #pragma unroll
  for (int k = 0; k < 4; k++) se2 += expf(mv[k] - mx2);
  #pragma unroll
  for (int d = 1; d < 64; d <<= 1) se2 += __shfl_xor(se2, d, 64);
  if (l == 0) red[2 + wv] = se2;
  __syncthreads();
  if (tid == 0) out[b] = mx2 + logf(red[2] + red[3]) - negbuf[b];
}

extern "C" void kernel_launch(void* const* d_in, const int* in_sizes, int n_in,
                              void* d_out, int out_size, void* d_ws, size_t ws_size,
                              hipStream_t stream)
{
  (void)in_sizes; (void)n_in; (void)out_size; (void)ws_size;
  const float* x = (const float*)d_in[0];
  const float* y = (const float*)d_in[1];
  float* out = (float*)d_out;
  char* ws = (char*)d_ws;
  uint16_t* xnb  = (uint16_t*)ws;
  uint16_t* ynb  = (uint16_t*)(ws + (size_t)16777216);
  uint16_t* skew = (uint16_t*)(ws + (size_t)33554432);
  float*  negbuf = (float*)  (ws + (size_t)75497472);

  (void)hipFuncSetAttribute((const void*)dtw_kernel,
                            hipFuncAttributeMaxDynamicSharedMemorySize, 72192);

  pad_zero_kernel<<<16384, 64, 0, stream>>>(skew);
  norm_cast_kernel<<<16384, 256, 0, stream>>>(x, y, xnb, ynb);
  gemm_cost_kernel<<<1024, 256, 0, stream>>>(xnb, ynb, skew);
  neg_lse_kernel<<<64, 256, 0, stream>>>(skew, negbuf);
  dtw_kernel<<<64, 128, 72192, stream>>>(skew, negbuf, out);
}

// Round 8
// 297.855 us; speedup vs baseline: 1.0120x; 1.0120x over previous
//
#include <hip/hip_runtime.h>
#include <hip/hip_bf16.h>
#include <stdint.h>

typedef __attribute__((ext_vector_type(8))) short short8v;     // 8 x bf16 (MFMA A/B frag)
typedef __attribute__((ext_vector_type(4))) float float4v;     // MFMA C/D frag / vec loads
typedef __attribute__((ext_vector_type(4))) unsigned short ushort4v;
typedef __attribute__((ext_vector_type(4))) unsigned int uint4v;

#define FINF __builtin_huge_valf()
#define BB 64
#define NN 512
#define DD 256
#define TT_SKEW 640   // skew rows: tau = r + 2*(j>>3) in [0, 511+126] -> pad to 640

// ws layout (bytes):
//   [0,        16777216)  xnb bf16 [B][N][D]
//   [16777216, 33554432)  ynb bf16 [B][N][D]
//   [33554432, 75497472)  cost_skew bf16 [B][640][512]  (cell (r,j) at row tau=r+2*(j>>3), col j)
//   [75497472, 75501568)  negbuf f32 [64] (+pad)
//   [75501568, 79695872)  decg u32 [B][16384]  (decision words)

static __device__ __forceinline__ unsigned short f2bf(float f) {
  union { float f; uint32_t u; } a; a.f = f;
  uint32_t r = a.u + 0x7fffu + ((a.u >> 16) & 1u);   // RNE
  return (unsigned short)(r >> 16);
}
static __device__ __forceinline__ float bf2f(uint16_t v) {
  return __uint_as_float(((uint32_t)v) << 16);
}

// ---------------- Kernel 0: zero the skew-layout pad cells ----------------
// (tau, group g) is pad iff r = tau - 2g outside [0,512). 16B per (tau,g).
__global__ __launch_bounds__(64) void pad_zero_kernel(uint16_t* __restrict__ skew)
{
  const int tau = blockIdx.x, b = blockIdx.y, g = threadIdx.x;
  const int r = tau - 2 * g;
  if (r < 0 || r > 511) {
    uint16_t* p = skew + ((size_t)b * TT_SKEW + tau) * NN + g * 8;
    *(uint4v*)p = (uint4v){0u, 0u, 0u, 0u};
  }
}

// ---------------- Kernel 1: row-normalize + cast to bf16 ----------------
__global__ __launch_bounds__(256) void norm_cast_kernel(
    const float* __restrict__ x, const float* __restrict__ y,
    uint16_t* __restrict__ xnb, uint16_t* __restrict__ ynb)
{
  const int wave = threadIdx.x >> 6, lane = threadIdx.x & 63;
  const int row = blockIdx.x * 4 + wave;
  const float* src; uint16_t* dst;
  if (row < BB * NN) { src = x + (size_t)row * DD;            dst = xnb + (size_t)row * DD; }
  else               { src = y + (size_t)(row - BB*NN) * DD;  dst = ynb + (size_t)(row - BB*NN) * DD; }
  const float4v v = *(const float4v*)(src + lane * 4);
  float s = v[0]*v[0] + v[1]*v[1] + v[2]*v[2] + v[3]*v[3];
  #pragma unroll
  for (int d = 1; d < 64; d <<= 1) s += __shfl_xor(s, d, 64);
  const float inv = 1.0f / fmaxf(sqrtf(s), 1e-8f);
  ushort4v o;
  o[0] = f2bf(v[0] * inv); o[1] = f2bf(v[1] * inv);
  o[2] = f2bf(v[2] * inv); o[3] = f2bf(v[3] * inv);
  *(ushort4v*)(dst + lane * 4) = o;
}

// ---------------- Kernel 2: cost = 1 - xn·yn -> bf16 skewed layout ----------------
__global__ __launch_bounds__(256) void gemm_cost_kernel(
    const uint16_t* __restrict__ xnb, const uint16_t* __restrict__ ynb,
    uint16_t* __restrict__ skew)
{
  __shared__ uint16_t As[128 * 32];
  __shared__ uint16_t Bs[128 * 32];
  const int bid = blockIdx.x;
  const int b = bid >> 4, tm = (bid >> 2) & 3, tn = bid & 3;
  const int tid = threadIdx.x, wave = tid >> 6, lane = tid & 63;
  const int wr = wave >> 1, wc = wave & 1;

  const char* Ab = (const char*)(xnb + (size_t)b * NN * DD + (size_t)tm * 128 * DD);
  const char* Bb = (const char*)(ynb + (size_t)b * NN * DD + (size_t)tn * 128 * DD);

  float4v acc[4][4];
  #pragma unroll
  for (int i = 0; i < 4; i++)
    #pragma unroll
    for (int j = 0; j < 4; j++) acc[i][j] = (float4v){0.f, 0.f, 0.f, 0.f};

  const int seg0 = wave * 2;
  const int o0 = seg0 * 1024 + lane * 16;
  const int o1 = o0 + 1024;
  const int r0 = o0 >> 6, c0 = o0 & 63;
  const int r1 = o1 >> 6, c1 = o1 & 63;

  for (int kk = 0; kk < 8; kk++) {
    const int kb = kk * 64;
    __builtin_amdgcn_global_load_lds(
        (const __attribute__((address_space(1))) uint32_t*)(Ab + (size_t)r0 * 512 + kb + c0),
        (__attribute__((address_space(3))) uint32_t*)((char*)As + seg0 * 1024), 16, 0, 0);
    __builtin_amdgcn_global_load_lds(
        (const __attribute__((address_space(1))) uint32_t*)(Ab + (size_t)r1 * 512 + kb + c1),
        (__attribute__((address_space(3))) uint32_t*)((char*)As + (seg0 + 1) * 1024), 16, 0, 0);
    __builtin_amdgcn_global_load_lds(
        (const __attribute__((address_space(1))) uint32_t*)(Bb + (size_t)r0 * 512 + kb + c0),
        (__attribute__((address_space(3))) uint32_t*)((char*)Bs + seg0 * 1024), 16, 0, 0);
    __builtin_amdgcn_global_load_lds(
        (const __attribute__((address_space(1))) uint32_t*)(Bb + (size_t)r1 * 512 + kb + c1),
        (__attribute__((address_space(3))) uint32_t*)((char*)Bs + (seg0 + 1) * 1024), 16, 0, 0);
    __syncthreads();

    short8v af[4], bfr[4];
    #pragma unroll
    for (int mi = 0; mi < 4; mi++) {
      const int rr = wr * 64 + mi * 16 + (lane & 15);
      af[mi] = *(const short8v*)((const char*)As + rr * 64 + (lane >> 4) * 16);
    }
    #pragma unroll
    for (int nj = 0; nj < 4; nj++) {
      const int rr = wc * 64 + nj * 16 + (lane & 15);
      bfr[nj] = *(const short8v*)((const char*)Bs + rr * 64 + (lane >> 4) * 16);
    }
    #pragma unroll
    for (int mi = 0; mi < 4; mi++)
      #pragma unroll
      for (int nj = 0; nj < 4; nj++)
        acc[mi][nj] = __builtin_amdgcn_mfma_f32_16x16x32_bf16(af[mi], bfr[nj], acc[mi][nj], 0, 0, 0);
    __syncthreads();
  }

  uint16_t* Cb = skew + (size_t)b * TT_SKEW * NN;
  #pragma unroll
  for (int mi = 0; mi < 4; mi++)
    #pragma unroll
    for (int nj = 0; nj < 4; nj++) {
      const int cc = tn * 128 + wc * 64 + nj * 16 + (lane & 15);
      const int lg = cc >> 3;
      #pragma unroll
      for (int v = 0; v < 4; v++) {
        const int rr = tm * 128 + wr * 64 + mi * 16 + (lane >> 4) * 4 + v;
        Cb[(size_t)(rr + 2 * lg) * NN + cc] = f2bf(1.0f - acc[mi][nj][v]);
      }
    }
}

// ---------------- Kernel 3: neg[b] = LSE over column sums ----------------
__global__ __launch_bounds__(256) void neg_lse_kernel(
    const uint16_t* __restrict__ skew, float* __restrict__ negbuf)
{
  __shared__ float sm[8];
  const int b = blockIdx.x, tid = threadIdx.x;
  const int wave = tid >> 6, lane = tid & 63;
  const uint32_t* p = (const uint32_t*)(skew + (size_t)b * TT_SKEW * NN) + tid;
  float s0 = 0.f, s1 = 0.f;
  #pragma unroll 8
  for (int t = 0; t < TT_SKEW; ++t) {
    const uint32_t w = p[t * 256];
    s0 += __uint_as_float(w << 16);
    s1 += __uint_as_float(w & 0xFFFF0000u);
  }
  float m = fmaxf(s0, s1);
  #pragma unroll
  for (int d = 1; d < 64; d <<= 1) m = fmaxf(m, __shfl_xor(m, d, 64));
  if (lane == 0) sm[wave] = m;
  __syncthreads();
  m = fmaxf(fmaxf(sm[0], sm[1]), fmaxf(sm[2], sm[3]));
  float e = expf(s0 - m) + expf(s1 - m);
  #pragma unroll
  for (int d = 1; d < 64; d <<= 1) e += __shfl_xor(e, d, 64);
  if (lane == 0) sm[4 + wave] = e;
  __syncthreads();
  if (tid == 0) negbuf[b] = m + logf(sm[4] + sm[5] + sm[6] + sm[7]);
}

// ---------------- Kernel 4: DTW forward, 2 rows/lane/step ----------------
// One 64-lane wave per batch. Lane l owns cols [8l,8l+8); step t processes
// rows r0=2(t-l), r1=r0+1. Skew (tau=r+2*(j>>3)) makes each step two
// contiguous 1KB wave loads (rows 2t, 2t+1). 16-deep register load ring,
// dataflow-tied s_waitcnt vmcnt(14). Boundary tc via 2 shfl_up + 1 carry.
// Decisions: u32/lane/step (2 rows x 8 cols x 2b), written to LDS then
// dumped to global for the separate backtrack kernel.
__global__ __launch_bounds__(64, 1) void dtw_fwd_kernel(
    const uint16_t* __restrict__ skew, uint32_t* __restrict__ decg)
{
  extern __shared__ char lds_raw[];
  const int l = threadIdx.x;
  const int b = blockIdx.x;
  const uint16_t* csk = skew + (size_t)b * TT_SKEW * NN;
  const uint64_t base = (uint64_t)(uintptr_t)csk;
  const bool is0 = (l == 0);
  const uint32_t voff_base = 16u * (uint32_t)l;

  uint4v ringA[8], ringB[8];     // rows 2t (A) and 2t+1 (B)
  #pragma unroll
  for (int i = 0; i < 8; ++i) {
    const uint32_t voA = voff_base + ((uint32_t)(2 * i) << 10);
    const uint32_t voB = voA + 1024u;
    asm volatile("global_load_dwordx4 %0, %1, %2" : "=v"(ringA[i]) : "v"(voA), "s"(base));
    asm volatile("global_load_dwordx4 %0, %1, %2" : "=v"(ringB[i]) : "v"(voB), "s"(base));
  }

  float tp[8];
  #pragma unroll
  for (int c = 0; c < 8; ++c) tp[c] = FINF;
  float cl0 = FINF, cl1 = FINF, carry = FINF;
  const uint32_t dump_addr = 65536u + (((uint32_t)l) << 2);

  for (int t0 = 0; t0 < 320; t0 += 8) {
    #pragma unroll
    for (int u = 0; u < 8; ++u) {
      const int t = t0 + u;
      float shA = __shfl_up(cl0, 1, 64);   // tc[r0][8l-1]
      float shB = __shfl_up(cl1, 1, 64);   // tc[r1][8l-1]
      if (is0) { shA = (t == 0) ? 0.0f : FINF; shB = FINF; }
      const float sh_p0 = carry;            // tc[r0-1][8l-1]
      carry = shB;

      asm volatile("s_waitcnt vmcnt(14)" : "+v"(ringA[u]), "+v"(ringB[u]));
      const uint4v A = ringA[u];
      const uint4v Bv = ringB[u];

      const uint32_t rlane = (uint32_t)(t - l);
      const bool valid = rlane < 256u;

      // unpack both rows + prefix sums
      float ca[8], cbv[8], S0[8], S1[8];
      #pragma unroll
      for (int k = 0; k < 4; ++k) {
        ca[2*k]   = __uint_as_float(A[k] << 16);
        ca[2*k+1] = __uint_as_float(A[k] & 0xFFFF0000u);
        cbv[2*k]   = __uint_as_float(Bv[k] << 16);
        cbv[2*k+1] = __uint_as_float(Bv[k] & 0xFFFF0000u);
      }
      S0[0] = ca[0]; S1[0] = cbv[0];
      #pragma unroll
      for (int c = 1; c < 8; ++c) { S0[c] = S0[c-1] + ca[c]; S1[c] = S1[c-1] + cbv[c]; }

      // ---- row 0 ----
      float dcp0[8], mu0[8], w0[8], PW0[8], tn0[8];
      dcp0[0] = sh_p0;
      #pragma unroll
      for (int c = 1; c < 8; ++c) dcp0[c] = tp[c-1];
      #pragma unroll
      for (int c = 0; c < 8; ++c) mu0[c] = fminf(dcp0[c], tp[c]);
      w0[0] = mu0[0];
      #pragma unroll
      for (int c = 1; c < 8; ++c) w0[c] = mu0[c] - S0[c-1];
      PW0[0] = w0[0];
      #pragma unroll
      for (int c = 1; c < 8; ++c) PW0[c] = fminf(PW0[c-1], w0[c]);
      #pragma unroll
      for (int c = 0; c < 8; ++c) tn0[c] = fminf(PW0[c], shA) + S0[c];

      // ---- row 1 (chains on row 0 in-lane) ----
      float dcp1[8], mu1[8], w1[8], PW1[8], tn1[8];
      dcp1[0] = shA;
      #pragma unroll
      for (int c = 1; c < 8; ++c) dcp1[c] = tn0[c-1];
      #pragma unroll
      for (int c = 0; c < 8; ++c) mu1[c] = fminf(dcp1[c], tn0[c]);
      w1[0] = mu1[0];
      #pragma unroll
      for (int c = 1; c < 8; ++c) w1[c] = mu1[c] - S1[c-1];
      PW1[0] = w1[0];
      #pragma unroll
      for (int c = 1; c < 8; ++c) PW1[c] = fminf(PW1[c-1], w1[c]);
      #pragma unroll
      for (int c = 0; c < 8; ++c) tn1[c] = fminf(PW1[c], shB) + S1[c];

      // ---- decisions (ref tie-break diag> up > left): dd=(lc<mu)?2:(up<dcp) ----
      uint32_t word = 0;
      {
        float lc0[8], lc1[8];
        lc0[0] = shA; lc1[0] = shB;
        #pragma unroll
        for (int c = 1; c < 8; ++c) { lc0[c] = tn0[c-1]; lc1[c] = tn1[c-1]; }
        #pragma unroll
        for (int c = 0; c < 8; ++c) {
          const uint32_t e0 = (tp[c] < dcp0[c]) ? 1u : 0u;
          const uint32_t d0 = (lc0[c] < mu0[c]) ? 2u : e0;
          const uint32_t e1 = (tn0[c] < dcp1[c]) ? 1u : 0u;
          const uint32_t d1 = (lc1[c] < mu1[c]) ? 2u : e1;
          word |= (d0 << (2 * c)) | (d1 << (16 + 2 * c));
        }
      }
      const uint32_t waddr = valid ? ((rlane << 8) | (((uint32_t)l) << 2)) : dump_addr;
      *(uint32_t*)(lds_raw + waddr) = word;

      #pragma unroll
      for (int c = 0; c < 8; ++c) tp[c] = valid ? tn1[c] : tp[c];
      cl0 = valid ? tn0[7] : cl0;
      cl1 = tp[7];

      // refill rows 2(t+8), 2(t+8)+1 (clamped; keeps exactly 16 in flight)
      {
        int rr = 2 * (t + 8); if (rr > 638) rr = 638;
        const uint32_t voA = voff_base + ((uint32_t)rr << 10);
        const uint32_t voB = voA + 1024u;
        asm volatile("global_load_dwordx4 %0, %1, %2" : "=v"(ringA[u]) : "v"(voA), "s"(base));
        asm volatile("global_load_dwordx4 %0, %1, %2" : "=v"(ringB[u]) : "v"(voB), "s"(base));
      }
    }
  }
  asm volatile("s_waitcnt vmcnt(0)" ::: "memory");

  // dump decisions to global (coalesced)
  uint32_t* dg = decg + (size_t)b * 16384;
  #pragma unroll 4
  for (int i = 0; i < 64; ++i)
    *(uint4v*)(dg + i * 256 + l * 4) = *(const uint4v*)(lds_raw + i * 1024 + l * 16);
}

// ---------------- Kernel 5: backtrack + colpos + pos LSE ----------------
// 64 lanes per batch. dec word [rp][l] covers rows {2rp, 2rp+1} cols [8l,8l+8):
// bit offset = (i&1)*16 + (j&7)*2.
__global__ __launch_bounds__(64, 1) void dtw_bt_kernel(
    const uint16_t* __restrict__ skew, const uint32_t* __restrict__ decg,
    const float* __restrict__ negbuf, float* __restrict__ out)
{
  extern __shared__ char lds_raw[];
  uint16_t* rlo    = (uint16_t*)(lds_raw + 65536);
  uint16_t* rhi    = (uint16_t*)(lds_raw + 66560);
  float*    colpos = (float*)  (lds_raw + 67584);
  const uint32_t* dec32 = (const uint32_t*)lds_raw;

  const int l = threadIdx.x;
  const int b = blockIdx.x;
  const uint16_t* csk = skew + (size_t)b * TT_SKEW * NN;
  const uint32_t* dg = decg + (size_t)b * 16384;

  #pragma unroll 4
  for (int i = 0; i < 64; ++i)
    *(uint4v*)(lds_raw + i * 1024 + l * 16) = *(const uint4v*)(dg + i * 256 + l * 4);
  for (int r = l; r < NN; r += 64) { rlo[r] = 1; rhi[r] = 0; colpos[r] = 0.0f; }
  __syncthreads();

  if (l == 0) {
    int i = NN - 1, j = NN - 1, hicur = NN - 1;
    int cidx = -1; uint32_t cw = 0;
    while (i > 0 && j > 0) {
      const int widx = (i >> 1) * 64 + (j >> 3);
      if (widx != cidx) { cw = dec32[widx]; cidx = widx; }
      const uint32_t dd = (cw >> (((i & 1) << 4) + ((j & 7) << 1))) & 3u;
      if (dd == 2u) { j--; }           // left: stay in row
      else {
        rlo[i] = (uint16_t)j; rhi[i] = (uint16_t)hicur;  // leave row i
        i--;
        if (dd == 0u) j--;             // diag also moves left
        hicur = j;                     // entry column of new row
      }
    }
    rlo[i] = (uint16_t)j; rhi[i] = (uint16_t)hicur;      // pending row at exit
  }
  __syncthreads();
  for (int r = l; r < NN; r += 64) {
    const int lo = rlo[r], hi = rhi[r];
    for (int j = lo; j <= hi; j++) {
      const float cv = bf2f(csk[(size_t)(r + 2 * (j >> 3)) * NN + j]);
      atomicAdd(&colpos[j], cv);
    }
  }
  if (l == 0 && rlo[0] != 0) atomicAdd(&colpos[0], bf2f(csk[0]));
  __syncthreads();

  float mv[8];
  float mx2 = -FINF;
  #pragma unroll
  for (int k = 0; k < 8; k++) { mv[k] = colpos[l + 64 * k]; mx2 = fmaxf(mx2, mv[k]); }
  #pragma unroll
  for (int d = 1; d < 64; d <<= 1) mx2 = fmaxf(mx2, __shfl_xor(mx2, d, 64));
  float se2 = 0.f;
  #pragma unroll
  for (int k = 0; k < 8; k++) se2 += expf(mv[k] - mx2);
  #pragma unroll
  for (int d = 1; d < 64; d <<= 1) se2 += __shfl_xor(se2, d, 64);
  const float pos = mx2 + logf(se2);

  if (l == 0) out[b] = pos - negbuf[b];
}

extern "C" void kernel_launch(void* const* d_in, const int* in_sizes, int n_in,
                              void* d_out, int out_size, void* d_ws, size_t ws_size,
                              hipStream_t stream)
{
  (void)in_sizes; (void)n_in; (void)out_size; (void)ws_size;
  const float* x = (const float*)d_in[0];
  const float* y = (const float*)d_in[1];
  float* out = (float*)d_out;
  char* ws = (char*)d_ws;
  uint16_t* xnb  = (uint16_t*)ws;
  uint16_t* ynb  = (uint16_t*)(ws + (size_t)16777216);
  uint16_t* skew = (uint16_t*)(ws + (size_t)33554432);
  float*  negbuf = (float*)  (ws + (size_t)75497472);
  uint32_t* decg = (uint32_t*)(ws + (size_t)75501568);

  (void)hipFuncSetAttribute((const void*)dtw_fwd_kernel,
                            hipFuncAttributeMaxDynamicSharedMemorySize, 65792);
  (void)hipFuncSetAttribute((const void*)dtw_bt_kernel,
                            hipFuncAttributeMaxDynamicSharedMemorySize, 69632);

  pad_zero_kernel<<<dim3(TT_SKEW, BB), 64, 0, stream>>>(skew);
  norm_cast_kernel<<<16384, 256, 0, stream>>>(x, y, xnb, ynb);
  gemm_cost_kernel<<<1024, 256, 0, stream>>>(xnb, ynb, skew);
  neg_lse_kernel<<<64, 256, 0, stream>>>(skew, negbuf);
  dtw_fwd_kernel<<<64, 64, 65792, stream>>>(skew, decg);
  dtw_bt_kernel<<<64, 64, 69632, stream>>>(skew, decg, negbuf, out);
}